// Round 6
// baseline (33.183 us; speedup 1.0000x reference)
//
#include <hip/hip_runtime.h>
#include <math.h>

#define HH   512
#define WW   512
#define KG   256
#define NPIX (HH * WW)
#define EPSF 1e-6f
#define LOG2E 1.4426950408889634f

// Software exp2: n = rint(e); f = e-n in [-0.5,0.5]; 2^f by degree-4 poly;
// scale by 2^n via v_ldexp_f32. 8 full-rate VALU insts (~16 cyc/wave) vs
// v_exp_f32's measured ~32 cyc pipe occupancy. Rel err ~2e-6.
__device__ __forceinline__ float fast_exp2(float e) {
    const float fn = rintf(e);               // v_rndne_f32
    const float f  = e - fn;                 // v_sub_f32
    const int   n  = (int)fn;                // v_cvt_i32_f32
    float p = fmaf(f, 0.0096181291f, 0.0555041087f);
    p = fmaf(f, p, 0.2402265069f);
    p = fmaf(f, p, 0.6931471806f);
    p = fmaf(f, p, 1.0f);
    return __builtin_amdgcn_ldexpf(p, n);    // v_ldexp_f32
}

// Single fused kernel (R3 structure). Each block folds the K=256 gaussians
// into 12-float polynomial form in LDS (once), then each thread renders ONE
// pixel, looping over all gaussians with wave-uniform broadcast LDS reads.
//   log2(w_k(x,y)) = ca*x^2 + cb*y^2 + cc*xy + cd*x + ce*y + cf
__global__ __launch_bounds__(256, 4) void gauss_render(
    const float* __restrict__ grid,          // (H,W,2)
    const float* __restrict__ mu,            // (K,2)
    const float* __restrict__ log_scales,    // (K,2)
    const float* __restrict__ theta,         // (K,)
    const float* __restrict__ color_logits,  // (K,3)
    const float* __restrict__ log_amp,       // (K,1)
    float* __restrict__ out)                 // (H,W,3)
{
    __shared__ float4 sp[3 * KG];   // 12 KB

    const int tid = threadIdx.x;
    {
        const int k = tid;                        // blockDim.x == KG == 256
        const float mx  = mu[2 * k + 0];
        const float my  = mu[2 * k + 1];
        const float sx  = expf(log_scales[2 * k + 0]);
        const float sy  = expf(log_scales[2 * k + 1]);
        const float isx = 1.0f / (sx * sx + EPSF);
        const float isy = 1.0f / (sy * sy + EPSF);
        const float t   = theta[k];
        const float c   = cosf(t);
        const float s   = sinf(t);

        const float A = c * c * isx + s * s * isy;
        const float B = s * s * isx + c * c * isy;
        const float C = 2.0f * c * s * (isx - isy);

        const float la  = log_amp[k];
        const float amp = (la > 20.0f) ? la : log1pf(expf(la));  // softplus
        const float lnA = logf(amp);

        const float ca = -0.5f * LOG2E * A;
        const float cb = -0.5f * LOG2E * B;
        const float cc = -0.5f * LOG2E * C;
        const float cd = LOG2E * (A * mx + 0.5f * C * my);
        const float ce = LOG2E * (B * my + 0.5f * C * mx);
        const float cf = LOG2E * (lnA - 0.5f * (A * mx * mx + B * my * my + C * mx * my));

        const float c0 = 1.0f / (1.0f + expf(-color_logits[3 * k + 0]));
        const float c1 = 1.0f / (1.0f + expf(-color_logits[3 * k + 1]));
        const float c2 = 1.0f / (1.0f + expf(-color_logits[3 * k + 2]));

        sp[3 * k + 0] = make_float4(ca, cb, cc, cd);
        sp[3 * k + 1] = make_float4(ce, cf, c0, c1);
        sp[3 * k + 2] = make_float4(c2, 0.0f, 0.0f, 0.0f);
    }
    __syncthreads();

    const int pix = blockIdx.x * 256 + tid;       // one pixel per thread

    const float2 p = reinterpret_cast<const float2*>(grid)[pix];
    const float X = p.x, Y = p.y;
    const float X2 = X * X, Y2 = Y * Y, XY = X * Y;

    float den = 0.f, R = 0.f, G = 0.f, B = 0.f;

    #pragma unroll 8
    for (int k = 0; k < KG; ++k) {
        const float4 q0 = sp[3 * k + 0];   // ca cb cc cd
        const float4 q1 = sp[3 * k + 1];   // ce cf c0 c1
        const float4 q2 = sp[3 * k + 2];   // c2 - - -

        float e = fmaf(q1.x, Y, q1.y);     // ce*y + cf
        e = fmaf(q0.w, X,  e);             // + cd*x
        e = fmaf(q0.z, XY, e);             // + cc*xy
        e = fmaf(q0.y, Y2, e);             // + cb*y^2
        e = fmaf(q0.x, X2, e);             // + ca*x^2

        const float w = fast_exp2(e);

        den += w;
        R = fmaf(w, q1.z, R);
        G = fmaf(w, q1.w, G);
        B = fmaf(w, q2.x, B);
    }

    const float inv = 1.0f / (den + EPSF);
    out[3 * pix + 0] = fminf(fmaxf(R * inv, 0.f), 1.f);
    out[3 * pix + 1] = fminf(fmaxf(G * inv, 0.f), 1.f);
    out[3 * pix + 2] = fminf(fmaxf(B * inv, 0.f), 1.f);
}

extern "C" void kernel_launch(void* const* d_in, const int* in_sizes, int n_in,
                              void* d_out, int out_size, void* d_ws, size_t ws_size,
                              hipStream_t stream) {
    const float* grid         = (const float*)d_in[0];
    const float* mu           = (const float*)d_in[1];
    const float* log_scales   = (const float*)d_in[2];
    const float* theta        = (const float*)d_in[3];
    const float* color_logits = (const float*)d_in[4];
    const float* log_amp      = (const float*)d_in[5];
    float* out = (float*)d_out;

    const int threads = 256;
    const int blocks  = NPIX / threads;          // 1024 blocks, 1 px/thread
    hipLaunchKernelGGL(gauss_render, dim3(blocks), dim3(threads), 0, stream,
                       grid, mu, log_scales, theta, color_logits, log_amp, out);
}

// Round 7
// 30.358 us; speedup vs baseline: 1.0931x; 1.0931x over previous
//
#include <hip/hip_runtime.h>
#include <hip/hip_fp16.h>
#include <math.h>

#define HH   512
#define WW   512
#define KG   256
#define NPIX (HH * WW)
#define EPSF 1e-6f
#define LOG2E 1.4426950408889634f

// 512 threads/block, split-K: tid<256 handles k in [0,128), tid>=256 handles
// [128,256) for the SAME pixel; partial (den,R,G,B) reduced through LDS.
// Params packed 32 B/gaussian -> 2x ds_read_b128 per iter:
//   sp0[k] = {ca, cb, cc, cd}
//   sp1[k] = {ce, cf, bitcast(half2(c0,c1)), c2}
//   log2(w_k(x,y)) = ca*x^2 + cb*y^2 + cc*xy + cd*x + ce*y + cf   (log2e folded)
__global__ __launch_bounds__(512, 8) void gauss_render(
    const float* __restrict__ grid,          // (H,W,2)
    const float* __restrict__ mu,            // (K,2)
    const float* __restrict__ log_scales,    // (K,2)
    const float* __restrict__ theta,         // (K,)
    const float* __restrict__ color_logits,  // (K,3)
    const float* __restrict__ log_amp,       // (K,1)
    float* __restrict__ out)                 // (H,W,3)
{
    __shared__ float4 sp0[KG];   // 4 KB
    __shared__ float4 sp1[KG];   // 4 KB
    __shared__ float4 red[256];  // 4 KB split-K reduction

    const int tid = threadIdx.x;
    if (tid < KG) {
        const int k = tid;
        const float mx  = mu[2 * k + 0];
        const float my  = mu[2 * k + 1];
        const float sx  = expf(log_scales[2 * k + 0]);
        const float sy  = expf(log_scales[2 * k + 1]);
        const float isx = 1.0f / (sx * sx + EPSF);
        const float isy = 1.0f / (sy * sy + EPSF);
        const float t   = theta[k];
        const float c   = cosf(t);
        const float s   = sinf(t);

        const float A = c * c * isx + s * s * isy;
        const float B = s * s * isx + c * c * isy;
        const float C = 2.0f * c * s * (isx - isy);

        const float la  = log_amp[k];
        const float amp = (la > 20.0f) ? la : log1pf(expf(la));  // softplus
        const float lnA = logf(amp);

        const float ca = -0.5f * LOG2E * A;
        const float cb = -0.5f * LOG2E * B;
        const float cc = -0.5f * LOG2E * C;
        const float cd = LOG2E * (A * mx + 0.5f * C * my);
        const float ce = LOG2E * (B * my + 0.5f * C * mx);
        const float cf = LOG2E * (lnA - 0.5f * (A * mx * mx + B * my * my + C * mx * my));

        const float c0 = 1.0f / (1.0f + expf(-color_logits[3 * k + 0]));
        const float c1 = 1.0f / (1.0f + expf(-color_logits[3 * k + 1]));
        const float c2 = 1.0f / (1.0f + expf(-color_logits[3 * k + 2]));

        const __half2 h01 = __floats2half2_rn(c0, c1);
        const float   hz  = __builtin_bit_cast(float, h01);

        sp0[k] = make_float4(ca, cb, cc, cd);
        sp1[k] = make_float4(ce, cf, hz, c2);
    }
    __syncthreads();

    const int pix  = blockIdx.x * 256 + (tid & 255);
    const int kbeg = (tid >> 8) * (KG / 2);          // 0 or 128

    const float2 p = reinterpret_cast<const float2*>(grid)[pix];
    const float X = p.x, Y = p.y;
    const float X2 = X * X, Y2 = Y * Y, XY = X * Y;

    float den = 0.f, R = 0.f, G = 0.f, B = 0.f;

    #pragma unroll 4
    for (int k = kbeg; k < kbeg + KG / 2; ++k) {
        const float4 q0 = sp0[k];   // ca cb cc cd
        const float4 q1 = sp1[k];   // ce cf h(c0,c1) c2

        float e = fmaf(q1.x, Y, q1.y);     // ce*y + cf
        e = fmaf(q0.w, X,  e);             // + cd*x
        e = fmaf(q0.z, XY, e);             // + cc*xy
        e = fmaf(q0.y, Y2, e);             // + cb*y^2
        e = fmaf(q0.x, X2, e);             // + ca*x^2

        const float w = __builtin_amdgcn_exp2f(e);

        const __half2 h   = __builtin_bit_cast(__half2, q1.z);
        const float2  c01 = __half22float2(h);

        den += w;
        R = fmaf(w, c01.x, R);
        G = fmaf(w, c01.y, G);
        B = fmaf(w, q1.w, B);
    }

    if (tid >= 256) {
        red[tid - 256] = make_float4(den, R, G, B);
    }
    __syncthreads();
    if (tid < 256) {
        const float4 o = red[tid];
        den += o.x; R += o.y; G += o.z; B += o.w;

        const float inv = 1.0f / (den + EPSF);
        out[3 * pix + 0] = fminf(fmaxf(R * inv, 0.f), 1.f);
        out[3 * pix + 1] = fminf(fmaxf(G * inv, 0.f), 1.f);
        out[3 * pix + 2] = fminf(fmaxf(B * inv, 0.f), 1.f);
    }
}

extern "C" void kernel_launch(void* const* d_in, const int* in_sizes, int n_in,
                              void* d_out, int out_size, void* d_ws, size_t ws_size,
                              hipStream_t stream) {
    const float* grid         = (const float*)d_in[0];
    const float* mu           = (const float*)d_in[1];
    const float* log_scales   = (const float*)d_in[2];
    const float* theta        = (const float*)d_in[3];
    const float* color_logits = (const float*)d_in[4];
    const float* log_amp      = (const float*)d_in[5];
    float* out = (float*)d_out;

    const int threads = 512;                    // 256 pixels/block, split-K x2
    const int blocks  = NPIX / 256;             // 1024 blocks -> 8192 waves
    hipLaunchKernelGGL(gauss_render, dim3(blocks), dim3(threads), 0, stream,
                       grid, mu, log_scales, theta, color_logits, log_amp, out);
}